// Round 7
// baseline (65.091 us; speedup 1.0000x reference)
//
#include <hip/hip_runtime.h>
#include <hip/hip_bf16.h>
#include <math.h>

using bf16x8 = __attribute__((ext_vector_type(8))) __bf16;
using bf16x4 = __attribute__((ext_vector_type(4))) __bf16;
using f32x4  = __attribute__((ext_vector_type(4))) float;

static constexpr int SEQ = 4096;
static constexpr int DIM = 64;
static constexpr int NB  = 4;
// 0.125 (1/sqrt(64)) * log2(e): scores land in log2 domain -> exp2 everywhere
static constexpr float QSCALE = 0.18033688011112042f;

__device__ __forceinline__ void gload16(const void* g, void* l) {
    __builtin_amdgcn_global_load_lds(
        (const __attribute__((address_space(1))) unsigned int*)g,
        (__attribute__((address_space(3))) unsigned int*)l,
        16, 0, 0);
}

__device__ __forceinline__ float fast_exp2(float x) {
#if __has_builtin(__builtin_amdgcn_exp2f)
    return __builtin_amdgcn_exp2f(x);
#else
    return exp2f(x);
#endif
}

// ---------------------------------------------------------------------------
// Kernel 0: cast+transpose W -> WT[slot][out][d] bf16, plus invf table.
// ---------------------------------------------------------------------------
__global__ __launch_bounds__(256)
void wprep_kernel(const float* __restrict__ w, __bf16* __restrict__ WT,
                  float* __restrict__ invf_tab)
{
    const int idx = (int)blockIdx.x * 256 + (int)threadIdx.x;  // < 3*64*64
    const int s = idx >> 12;
    const int o = (idx >> 6) & 63;
    const int d = idx & 63;
    WT[idx] = (__bf16)w[(s * DIM + d) * DIM + o];
    if (idx < 64)
        invf_tab[idx] = exp2f(-13.287712379549449f * ((float)idx * 0.03125f));
}

// ---------------------------------------------------------------------------
// Kernel 1: fused pos-embed + QKV projection, 3 slots in one pass (x-load +
// trig once). Block = 256 thr (4 waves), wave owns 16 rows. grid = B*S/64.
// Q pre-scaled by QSCALE (log2 domain). V stored k-permuted: within each
// 64-k block, kl = 32h+16b4+4g+r lives at pos = 32h+8g+4b4+r.
// ---------------------------------------------------------------------------
__global__ __launch_bounds__(256)
void qkv_prep_kernel(const float* __restrict__ x, const __bf16* __restrict__ WT,
                     const float* __restrict__ invf_tab,
                     __bf16* __restrict__ Qb, __bf16* __restrict__ Kb,
                     __bf16* __restrict__ VTb)
{
    const int tid  = (int)threadIdx.x;
    const int lane = tid & 63;
    const int g  = lane >> 4;
    const int cl = lane & 15;
    const int rowbase = (int)blockIdx.x * 64 + (tid >> 6) * 16;  // in [0, B*S)

    const int row  = rowbase + cl;
    const int spos = row & (SEQ - 1);
    const float fpos = (float)spos;
    bf16x8 xa[2];
#pragma unroll
    for (int h = 0; h < 2; ++h) {
        const float* xp = x + (long)row * DIM + 32*h + 8*g;
        f32x4 x0 = *reinterpret_cast<const f32x4*>(xp);
        f32x4 x1 = *reinterpret_cast<const f32x4*>(xp + 4);
        f32x4 iv0 = *reinterpret_cast<const f32x4*>(invf_tab + 32*h + 8*g);
        f32x4 iv1 = *reinterpret_cast<const f32x4*>(invf_tab + 32*h + 8*g + 4);
        bf16x8 v;
#pragma unroll
        for (int e = 0; e < 8; ++e) {
            const float invf = (e < 4) ? iv0[e] : iv1[e - 4];
            const float pe   = __sinf(fpos * invf);
            const float xv   = (e < 4) ? x0[e] : x1[e - 4];
            v[e] = (__bf16)(xv + pe);
        }
        xa[h] = v;
    }

#pragma unroll
    for (int slot = 0; slot < 3; ++slot) {
        const __bf16* wt = WT + slot * DIM * DIM;
        f32x4 acc[4];
#pragma unroll
        for (int nt = 0; nt < 4; ++nt) acc[nt] = (f32x4){0.f, 0.f, 0.f, 0.f};
#pragma unroll
        for (int nt = 0; nt < 4; ++nt) {
            bf16x8 w0 = *reinterpret_cast<const bf16x8*>(wt + (nt*16 + cl) * DIM + 8*g);
            bf16x8 w1 = *reinterpret_cast<const bf16x8*>(wt + (nt*16 + cl) * DIM + 32 + 8*g);
            acc[nt] = __builtin_amdgcn_mfma_f32_16x16x32_bf16(xa[0], w0, acc[nt], 0, 0, 0);
            acc[nt] = __builtin_amdgcn_mfma_f32_16x16x32_bf16(xa[1], w1, acc[nt], 0, 0, 0);
        }

        // C/D layout (HW-verified): lane l, reg r -> row (l>>4)*4+r, col l&15.
        if (slot < 2) {
            __bf16* dst = (slot == 0) ? Qb : Kb;
            const float scale = (slot == 0) ? QSCALE : 1.0f;
#pragma unroll
            for (int nt = 0; nt < 4; ++nt)
#pragma unroll
                for (int r = 0; r < 4; ++r) {
                    const int ro = rowbase + 4*g + r;
                    dst[(long)ro * DIM + nt*16 + cl] = (__bf16)(acc[nt][r] * scale);
                }
        } else {
            const int bi   = rowbase >> 12;
            const int sp   = rowbase & (SEQ - 1);
            const int kblk = sp & ~63;
            const int pos0 = 32 * ((rowbase >> 5) & 1) + 8*g + 4 * ((rowbase >> 4) & 1);
#pragma unroll
            for (int nt = 0; nt < 4; ++nt) {
                bf16x4 pk;
#pragma unroll
                for (int r = 0; r < 4; ++r) pk[r] = (__bf16)acc[nt][r];
                *reinterpret_cast<bf16x4*>(VTb + ((long)bi*DIM + nt*16 + cl) * SEQ + kblk + pos0) = pk;
            }
        }
    }
}

// ---------------------------------------------------------------------------
// Kernel 2: flash attention. 16 waves (1024 thr): wq = w&3 picks the 16-q
// sub-tile (block owns 64 q-rows), wk = w>>2 picks the k-quarter of this
// block's k-range. KSPLIT: blockIdx.y selects a SEQ/KSPLIT k-range; KSPLIT=2
// gives 512 blocks = 2 independent blocks/CU = 32 waves/CU, partials merged
// by combine_kernel. Per iter the block stages 4x(4KB K + 4KB V) = 32KB via
// global_load_lds, double-buffered; K chunk [32][64] XOR-swizzle (row&7);
// V chunk [64][32] XOR-swizzle ((drow>>1)&3). Softmax log2-domain, defer-max,
// per-lane deferred psum. 4-way wk merge through LDS (aliased staging bufs).
// ---------------------------------------------------------------------------
template<int KSPLIT>
__global__ __launch_bounds__(1024)
void attn_kernel(const __bf16* __restrict__ Qb, const __bf16* __restrict__ Kb,
                 const __bf16* __restrict__ VTb, float* __restrict__ out,
                 float* __restrict__ partial, float* __restrict__ mlbuf)
{
    constexpr int NITER = 32 / KSPLIT;
    constexpr int KW    = SEQ / KSPLIT / 4;     // k per wave

    __shared__ char smem[65536];
    __bf16* sK = (__bf16*)smem;              // [2][4][32][64]
    __bf16* sV = (__bf16*)(smem + 32768);    // [2][4][64][32]

    const int tid  = (int)threadIdx.x;
    const int w    = tid >> 6;
    const int lane = tid & 63;
    const int g  = lane >> 4;
    const int cl = lane & 15;
    const int wq = w & 3;
    const int wk = w >> 2;

    const int bid = (int)blockIdx.x;
    const int x8  = bid & 7;
    const int b   = x8 & 3;
    const int qt  = ((x8 >> 2) << 5) | (bid >> 3);   // [0,64), bijective
    const int qbase = qt * 64;
    const long kh_off = (long)blockIdx.y * (SEQ / KSPLIT);

    const __bf16* Qp = Qb  + ((long)b * SEQ + qbase + wq*16) * DIM;
    const __bf16* Kp = Kb  + (long)b * SEQ * DIM;
    const __bf16* Vp = VTb + (long)b * DIM * SEQ;

    // staging: thread stages one 16B K slot and one 16B V slot per iter
    const int ws_ = tid >> 8;                  // staged wk quarter 0..3
    const int ksr = (tid >> 3) & 31;           // K row within chunk
    const int kcs = (tid & 7) ^ (ksr & 7);     // inverse-swizzled source chunk
    const __bf16* srcK = Kp + (kh_off + ws_*KW + ksr) * DIM + kcs*8;

    const int vdr = (tid >> 2) & 63;           // V d-row
    const int vcs = (tid & 3) ^ ((vdr >> 1) & 3);
    const __bf16* srcV = Vp + (long)vdr * SEQ + kh_off + ws_*KW + vcs*8;

    __bf16* dstK = sK + tid*8;                 // + buf*8192
    __bf16* dstV = sV + tid*8;

    // Q fragments (held whole kernel)
    bf16x8 qf0 = *reinterpret_cast<const bf16x8*>(Qp + cl*DIM + 8*g);
    bf16x8 qf1 = *reinterpret_cast<const bf16x8*>(Qp + cl*DIM + 32 + 8*g);

    f32x4 acc[4];
#pragma unroll
    for (int nt = 0; nt < 4; ++nt) acc[nt] = (f32x4){0.f, 0.f, 0.f, 0.f};
    float mrun = -INFINITY;
    float lsum = 0.f;   // per-lane partial (cross-lane reduced in epilogue)

    // swizzled read offsets
    const int kswz0 = (( g      ^ (cl & 7)) << 4);
    const int kswz1 = (((g + 4) ^ (cl & 7)) << 4);
    const int vswz  = (( g ^ ((cl >> 1) & 3)) << 4);

    // prologue: stage chunk 0
    gload16(srcK, dstK);
    gload16(srcV, dstV);
    __syncthreads();

    int buf = 0;
#pragma unroll 1
    for (int n = 0; n < NITER; ++n) {
        if (n < NITER - 1) {
            gload16(srcK + (long)(n + 1) * 32 * DIM, dstK + (buf^1)*8192);
            gload16(srcV + (n + 1) * 32,             dstV + (buf^1)*8192);
        }

        const char* Kl = (const char*)(sK + buf*8192 + wk*2048);
        const char* Vl = (const char*)(sV + buf*8192 + wk*2048);

        // ---- scores: S^T tiles via mfma(K, Q), 32 k per iter ----
        f32x4 s[2];
#pragma unroll
        for (int kt = 0; kt < 2; ++kt) {
            const int row = kt*16 + cl;
            bf16x8 kf0 = *reinterpret_cast<const bf16x8*>(Kl + row*128 + kswz0);
            bf16x8 kf1 = *reinterpret_cast<const bf16x8*>(Kl + row*128 + kswz1);
            f32x4 z = (f32x4){0.f, 0.f, 0.f, 0.f};
            z = __builtin_amdgcn_mfma_f32_16x16x32_bf16(kf0, qf0, z, 0, 0, 0);
            z = __builtin_amdgcn_mfma_f32_16x16x32_bf16(kf1, qf1, z, 0, 0, 0);
            s[kt] = z;   // s[kt][r] = score_log2(q=cl, k = kt*16 + 4g + r)
        }

        // ---- online softmax (log2 domain) for q-row cl ----
        float tmax = fmaxf(fmaxf(fmaxf(s[0][0], s[0][1]), fmaxf(s[0][2], s[0][3])),
                           fmaxf(fmaxf(s[1][0], s[1][1]), fmaxf(s[1][2], s[1][3])));
        tmax = fmaxf(tmax, __shfl_xor(tmax, 16));
        tmax = fmaxf(tmax, __shfl_xor(tmax, 32));

        // defer-max: exact skip (THR=0) when no row's max grew
        if (!__all(tmax <= mrun)) {
            const float mnew = fmaxf(mrun, tmax);
            const float corr = fast_exp2(mrun - mnew);   // first iter: 0
            lsum *= corr;
#pragma unroll
            for (int r = 0; r < 4; ++r) {
                const float cr = __shfl(corr, 4*g + r);
#pragma unroll
                for (int nt = 0; nt < 4; ++nt) acc[nt][r] *= cr;
            }
            mrun = mnew;
        }

#pragma unroll
        for (int kt = 0; kt < 2; ++kt)
#pragma unroll
            for (int r = 0; r < 4; ++r) {
                const float p = fast_exp2(s[kt][r] - mrun);
                s[kt][r] = p;
                lsum += p;
            }

        // ---- pack P: pa[e] = P[cl][16*(e>>2) + 4g + (e&3)] ----
        bf16x8 pa;
#pragma unroll
        for (int e = 0; e < 8; ++e) pa[e] = (__bf16)s[e >> 2][e & 3];

        // ---- PV: one 16B V-frag + one MFMA per nt (k-permuted VT) ----
#pragma unroll
        for (int nt = 0; nt < 4; ++nt) {
            const int row = nt*16 + cl;
            bf16x8 vf = *reinterpret_cast<const bf16x8*>(Vl + row*64 + vswz);
            acc[nt] = __builtin_amdgcn_mfma_f32_16x16x32_bf16(pa, vf, acc[nt], 0, 0, 0);
        }

        __syncthreads();
        buf ^= 1;
    }

    // deferred psum cross-lane reduce (row cl spread over lanes cl+16g)
    lsum += __shfl_xor(lsum, 16);
    lsum += __shfl_xor(lsum, 32);

    // ---- 4-way wk merge through LDS (aliases dead staging buffers) ----
    float* lacc = (float*)smem;                  // [12][16][65] f32
    float* lm   = (float*)(smem + 49920);
    float* ll   = (float*)(smem + 50688);

    if (wk > 0) {
        const int pi = (wk - 1) * 4 + wq;
        if (lane < 16) { lm[pi*16 + lane] = mrun; ll[pi*16 + lane] = lsum; }
#pragma unroll
        for (int nt = 0; nt < 4; ++nt)
#pragma unroll
            for (int r = 0; r < 4; ++r)
                lacc[pi*1040 + (4*g + r)*65 + nt*16 + cl] = acc[nt][r];
    }
    __syncthreads();

    if (wk == 0) {
#pragma unroll
        for (int r = 0; r < 4; ++r) {
            const int ro = 4*g + r;
            const float mo = __shfl(mrun, ro);
            const float lo = __shfl(lsum, ro);
            const float m1 = lm[(wq     )*16 + ro], l1 = ll[(wq     )*16 + ro];
            const float m2 = lm[(4 + wq )*16 + ro], l2 = ll[(4 + wq )*16 + ro];
            const float m3 = lm[(8 + wq )*16 + ro], l3 = ll[(8 + wq )*16 + ro];
            const float M  = fmaxf(fmaxf(mo, m1), fmaxf(m2, m3));
            const float f0 = fast_exp2(mo - M);
            const float f1 = fast_exp2(m1 - M);
            const float f2 = fast_exp2(m2 - M);
            const float f3 = fast_exp2(m3 - M);
            const float L  = lo*f0 + l1*f1 + l2*f2 + l3*f3;
            const long rowg = (long)b * SEQ + qbase + wq*16 + ro;

            if constexpr (KSPLIT == 2) {
                if (cl == 0)
                    *reinterpret_cast<float2*>(mlbuf + ((long)blockIdx.y * NB * SEQ + rowg) * 2)
                        = make_float2(M, L);
#pragma unroll
                for (int nt = 0; nt < 4; ++nt) {
                    const int col = nt*16 + cl;
                    const float val = acc[nt][r]*f0
                        + lacc[(wq    )*1040 + ro*65 + col]*f1
                        + lacc[(4 + wq)*1040 + ro*65 + col]*f2
                        + lacc[(8 + wq)*1040 + ro*65 + col]*f3;
                    partial[(long)blockIdx.y * NB * SEQ * DIM + rowg * DIM + col] = val;
                }
            } else {
                const float inv = 1.f / L;
#pragma unroll
                for (int nt = 0; nt < 4; ++nt) {
                    const int col = nt*16 + cl;
                    const float val = acc[nt][r]*f0
                        + lacc[(wq    )*1040 + ro*65 + col]*f1
                        + lacc[(4 + wq)*1040 + ro*65 + col]*f2
                        + lacc[(8 + wq)*1040 + ro*65 + col]*f3;
                    out[rowg * DIM + col] = val * inv;
                }
            }
        }
    }
}

// ---------------------------------------------------------------------------
// Kernel 3: combine the two global split-K partials.
// ---------------------------------------------------------------------------
__global__ __launch_bounds__(256)
void combine_kernel(const float* __restrict__ partial,
                    const float* __restrict__ mlbuf, float* __restrict__ out)
{
    const int idx = (int)blockIdx.x * 256 + (int)threadIdx.x;  // < B*S*D/4
    const int row = idx >> 4;
    const float2 ml0 = *reinterpret_cast<const float2*>(mlbuf + (long)row * 2);
    const float2 ml1 = *reinterpret_cast<const float2*>(mlbuf + ((long)NB*SEQ + row) * 2);
    const float M  = fmaxf(ml0.x, ml1.x);
    const float f0 = fast_exp2(ml0.x - M);
    const float f1 = fast_exp2(ml1.x - M);
    const float inv = 1.f / (ml0.y*f0 + ml1.y*f1);
    f32x4 p0 = *reinterpret_cast<const f32x4*>(partial + (long)idx*4);
    f32x4 p1 = *reinterpret_cast<const f32x4*>(partial + (long)NB*SEQ*DIM + (long)idx*4);
    f32x4 o;
#pragma unroll
    for (int j = 0; j < 4; ++j) o[j] = (p0[j]*f0 + p1[j]*f1) * inv;
    *reinterpret_cast<f32x4*>(out + (long)idx*4) = o;
}

// ---------------------------------------------------------------------------
extern "C" void kernel_launch(void* const* d_in, const int* in_sizes, int n_in,
                              void* d_out, int out_size, void* d_ws, size_t ws_size,
                              hipStream_t stream)
{
    const float* x = (const float*)d_in[0];
    const float* w = (const float*)d_in[1];
    float* out = (float*)d_out;

    char* ws = (char*)d_ws;
    const size_t sz = (size_t)NB * SEQ * DIM * sizeof(__bf16);  // 2 MiB each
    __bf16* Qb   = (__bf16*)(ws);
    __bf16* Kb   = (__bf16*)(ws + sz);
    __bf16* VTb  = (__bf16*)(ws + 2 * sz);
    __bf16* WT   = (__bf16*)(ws + 3 * sz);              // 24 KiB
    float*  ivt  = (float*)(ws + 3 * sz + 24 * 1024);   // 256 B
    char*   base2 = ws + 3 * sz + 32 * 1024;
    float*  partial = (float*)base2;                    // 2 x 4 MiB f32
    float*  mlbuf   = (float*)(base2 + 2 * (size_t)NB * SEQ * DIM * 4);  // 256 KiB
    const size_t needed = (size_t)(3 * sz + 32 * 1024)
                        + 2 * (size_t)NB * SEQ * DIM * 4
                        + 2 * (size_t)NB * SEQ * 2 * 4;

    wprep_kernel<<<3 * DIM * DIM / 256, 256, 0, stream>>>(w, WT, ivt);

    qkv_prep_kernel<<<NB * SEQ / 64, 256, 0, stream>>>(x, WT, ivt, Qb, Kb, VTb);

    if (ws_size >= needed) {
        dim3 ga(NB * SEQ / 64, 2);
        attn_kernel<2><<<ga, 1024, 0, stream>>>(Qb, Kb, VTb, out, partial, mlbuf);
        combine_kernel<<<NB * SEQ * DIM / 4 / 256, 256, 0, stream>>>(partial, mlbuf, out);
    } else {
        dim3 ga(NB * SEQ / 64, 1);
        attn_kernel<1><<<ga, 1024, 0, stream>>>(Qb, Kb, VTb, out, nullptr, nullptr);
    }
}

// Round 8
// 55.887 us; speedup vs baseline: 1.1647x; 1.1647x over previous
//
#include <hip/hip_runtime.h>
#include <hip/hip_bf16.h>
#include <math.h>

using bf16x8 = __attribute__((ext_vector_type(8))) __bf16;
using bf16x4 = __attribute__((ext_vector_type(4))) __bf16;
using f32x4  = __attribute__((ext_vector_type(4))) float;

static constexpr int SEQ = 4096;
static constexpr int DIM = 64;
static constexpr int NB  = 4;
// 0.125 (1/sqrt(64)) * log2(e): scores land in log2 domain -> exp2 everywhere
static constexpr float QSCALE = 0.18033688011112042f;

__device__ __forceinline__ void gload16(const void* g, void* l) {
    __builtin_amdgcn_global_load_lds(
        (const __attribute__((address_space(1))) unsigned int*)g,
        (__attribute__((address_space(3))) unsigned int*)l,
        16, 0, 0);
}

__device__ __forceinline__ float fast_exp2(float x) {
#if __has_builtin(__builtin_amdgcn_exp2f)
    return __builtin_amdgcn_exp2f(x);
#else
    return exp2f(x);
#endif
}

// ---------------------------------------------------------------------------
// Kernel 0: cast+transpose W -> WT[slot][out][d] bf16, plus invf table.
// ---------------------------------------------------------------------------
__global__ __launch_bounds__(256)
void wprep_kernel(const float* __restrict__ w, __bf16* __restrict__ WT,
                  float* __restrict__ invf_tab)
{
    const int idx = (int)blockIdx.x * 256 + (int)threadIdx.x;  // < 3*64*64
    const int s = idx >> 12;
    const int o = (idx >> 6) & 63;
    const int d = idx & 63;
    WT[idx] = (__bf16)w[(s * DIM + d) * DIM + o];
    if (idx < 64)
        invf_tab[idx] = exp2f(-13.287712379549449f * ((float)idx * 0.03125f));
}

// ---------------------------------------------------------------------------
// Kernel 1: fused pos-embed + QKV projection, 3 slots in one pass (x-load +
// trig once). Block = 256 thr (4 waves), wave owns 16 rows. grid = B*S/64.
// Q pre-scaled by QSCALE (log2 domain). V stored k-permuted: within each
// 64-k block, kl = 32h+16b4+4g+r lives at pos = 32h+8g+4b4+r.
// ---------------------------------------------------------------------------
__global__ __launch_bounds__(256)
void qkv_prep_kernel(const float* __restrict__ x, const __bf16* __restrict__ WT,
                     const float* __restrict__ invf_tab,
                     __bf16* __restrict__ Qb, __bf16* __restrict__ Kb,
                     __bf16* __restrict__ VTb)
{
    const int tid  = (int)threadIdx.x;
    const int lane = tid & 63;
    const int g  = lane >> 4;
    const int cl = lane & 15;
    const int rowbase = (int)blockIdx.x * 64 + (tid >> 6) * 16;  // in [0, B*S)

    const int row  = rowbase + cl;
    const int spos = row & (SEQ - 1);
    const float fpos = (float)spos;
    bf16x8 xa[2];
#pragma unroll
    for (int h = 0; h < 2; ++h) {
        const float* xp = x + (long)row * DIM + 32*h + 8*g;
        f32x4 x0 = *reinterpret_cast<const f32x4*>(xp);
        f32x4 x1 = *reinterpret_cast<const f32x4*>(xp + 4);
        f32x4 iv0 = *reinterpret_cast<const f32x4*>(invf_tab + 32*h + 8*g);
        f32x4 iv1 = *reinterpret_cast<const f32x4*>(invf_tab + 32*h + 8*g + 4);
        bf16x8 v;
#pragma unroll
        for (int e = 0; e < 8; ++e) {
            const float invf = (e < 4) ? iv0[e] : iv1[e - 4];
            const float pe   = __sinf(fpos * invf);
            const float xv   = (e < 4) ? x0[e] : x1[e - 4];
            v[e] = (__bf16)(xv + pe);
        }
        xa[h] = v;
    }

#pragma unroll
    for (int slot = 0; slot < 3; ++slot) {
        const __bf16* wt = WT + slot * DIM * DIM;
        f32x4 acc[4];
#pragma unroll
        for (int nt = 0; nt < 4; ++nt) acc[nt] = (f32x4){0.f, 0.f, 0.f, 0.f};
#pragma unroll
        for (int nt = 0; nt < 4; ++nt) {
            bf16x8 w0 = *reinterpret_cast<const bf16x8*>(wt + (nt*16 + cl) * DIM + 8*g);
            bf16x8 w1 = *reinterpret_cast<const bf16x8*>(wt + (nt*16 + cl) * DIM + 32 + 8*g);
            acc[nt] = __builtin_amdgcn_mfma_f32_16x16x32_bf16(xa[0], w0, acc[nt], 0, 0, 0);
            acc[nt] = __builtin_amdgcn_mfma_f32_16x16x32_bf16(xa[1], w1, acc[nt], 0, 0, 0);
        }

        // C/D layout (HW-verified): lane l, reg r -> row (l>>4)*4+r, col l&15.
        if (slot < 2) {
            __bf16* dst = (slot == 0) ? Qb : Kb;
            const float scale = (slot == 0) ? QSCALE : 1.0f;
#pragma unroll
            for (int nt = 0; nt < 4; ++nt)
#pragma unroll
                for (int r = 0; r < 4; ++r) {
                    const int ro = rowbase + 4*g + r;
                    dst[(long)ro * DIM + nt*16 + cl] = (__bf16)(acc[nt][r] * scale);
                }
        } else {
            const int bi   = rowbase >> 12;
            const int sp   = rowbase & (SEQ - 1);
            const int kblk = sp & ~63;
            const int pos0 = 32 * ((rowbase >> 5) & 1) + 8*g + 4 * ((rowbase >> 4) & 1);
#pragma unroll
            for (int nt = 0; nt < 4; ++nt) {
                bf16x4 pk;
#pragma unroll
                for (int r = 0; r < 4; ++r) pk[r] = (__bf16)acc[nt][r];
                *reinterpret_cast<bf16x4*>(VTb + ((long)bi*DIM + nt*16 + cl) * SEQ + kblk + pos0) = pk;
            }
        }
    }
}

// ---------------------------------------------------------------------------
// Kernel 2: flash attention, deep-pipelined LDS staging (T3/T4 minimal form).
// 16 waves (1024 thr): wq = w&3 picks the 16-q sub-tile (block owns 64
// q-rows), wk = w>>2 picks the k-quarter, 32-k chunks, 32 iters.
// TRIPLE-buffered staging (3 x 32KB LDS): iter n issues stage(n+2), computes
// tile n, then `s_waitcnt vmcnt(2)` (waits ONLY for stage(n+1), issued a full
// iteration earlier) + raw s_barrier. No vmcnt(0) drain in the main loop ->
// staging latency hidden 2-deep. K chunk [32][64] XOR-swizzle (row&7);
// V chunk [64][32] XOR-swizzle ((drow>>1)&3); linear LDS dest +
// inverse-swizzled global source + swizzled read address.
// s_setprio(1) around MFMA clusters (T5). Softmax log2-domain, defer-max,
// per-lane deferred psum. 4-way wk merge through LDS (aliased staging bufs).
// grid = 256 (1 block/CU), XCD-batch swizzle b=f(bid&7).
// ---------------------------------------------------------------------------
__global__ __launch_bounds__(1024)
void attn_kernel(const __bf16* __restrict__ Qb, const __bf16* __restrict__ Kb,
                 const __bf16* __restrict__ VTb, float* __restrict__ out)
{
    __shared__ char smem[98304];   // 3 bufs x (16KB K + 16KB V)

    const int tid  = (int)threadIdx.x;
    const int w    = tid >> 6;
    const int lane = tid & 63;
    const int g  = lane >> 4;
    const int cl = lane & 15;
    const int wq = w & 3;
    const int wk = w >> 2;

    const int bid = (int)blockIdx.x;
    const int x8  = bid & 7;
    const int b   = x8 & 3;
    const int qt  = ((x8 >> 2) << 5) | (bid >> 3);   // [0,64), bijective
    const int qbase = qt * 64;

    const __bf16* Qp = Qb  + ((long)b * SEQ + qbase + wq*16) * DIM;
    const __bf16* Kp = Kb  + (long)b * SEQ * DIM;
    const __bf16* Vp = VTb + (long)b * DIM * SEQ;

    // staging: thread stages one 16B K slot and one 16B V slot per iter
    const int ws_ = tid >> 8;                  // staged wk quarter 0..3
    const int ksr = (tid >> 3) & 31;           // K row within chunk
    const int kcs = (tid & 7) ^ (ksr & 7);     // inverse-swizzled source chunk
    const __bf16* srcK = Kp + (long)(ws_*1024 + ksr) * DIM + kcs*8;

    const int vdr = (tid >> 2) & 63;           // V d-row
    const int vcs = (tid & 3) ^ ((vdr >> 1) & 3);
    const __bf16* srcV = Vp + (long)vdr * SEQ + ws_*1024 + vcs*8;

    // Q fragments (held whole kernel)
    bf16x8 qf0 = *reinterpret_cast<const bf16x8*>(Qp + cl*DIM + 8*g);
    bf16x8 qf1 = *reinterpret_cast<const bf16x8*>(Qp + cl*DIM + 32 + 8*g);

    f32x4 acc[4];
#pragma unroll
    for (int nt = 0; nt < 4; ++nt) acc[nt] = (f32x4){0.f, 0.f, 0.f, 0.f};
    float mrun = -INFINITY;
    float lsum = 0.f;   // per-lane partial (cross-lane reduced in epilogue)

    // swizzled read offsets
    const int kswz0 = (( g      ^ (cl & 7)) << 4);
    const int kswz1 = (((g + 4) ^ (cl & 7)) << 4);
    const int vswz  = (( g ^ ((cl >> 1) & 3)) << 4);

    // prologue: stage tiles 0 and 1, wait only for tile 0
    gload16(srcK,            smem + tid*16);
    gload16(srcV,            smem + 16384 + tid*16);
    gload16(srcK + 32*DIM,   smem + 32768 + tid*16);
    gload16(srcV + 32,       smem + 32768 + 16384 + tid*16);
    asm volatile("s_waitcnt vmcnt(2)" ::: "memory");
    __builtin_amdgcn_s_barrier();

    int bcur = 0;
#pragma unroll 1
    for (int n = 0; n < 32; ++n) {
        if (n < 30) {
            int bnext = bcur + 2; if (bnext >= 3) bnext -= 3;
            char* dst = smem + bnext*32768 + tid*16;
            gload16(srcK + (long)(n + 2) * 32 * DIM, dst);
            gload16(srcV + (n + 2) * 32,             dst + 16384);
            __builtin_amdgcn_sched_barrier(0);
        }

        const char* Kl = smem + bcur*32768 + wk*4096;
        const char* Vl = smem + bcur*32768 + 16384 + wk*4096;

        // ---- scores: S^T tiles via mfma(K, Q), 32 k per iter ----
        bf16x8 kf0 = *reinterpret_cast<const bf16x8*>(Kl + cl*128 + kswz0);
        bf16x8 kf1 = *reinterpret_cast<const bf16x8*>(Kl + cl*128 + kswz1);
        bf16x8 kf2 = *reinterpret_cast<const bf16x8*>(Kl + (16 + cl)*128 + kswz0);
        bf16x8 kf3 = *reinterpret_cast<const bf16x8*>(Kl + (16 + cl)*128 + kswz1);
        f32x4 s0 = (f32x4){0.f, 0.f, 0.f, 0.f};
        f32x4 s1 = (f32x4){0.f, 0.f, 0.f, 0.f};
        __builtin_amdgcn_s_setprio(1);
        s0 = __builtin_amdgcn_mfma_f32_16x16x32_bf16(kf0, qf0, s0, 0, 0, 0);
        s0 = __builtin_amdgcn_mfma_f32_16x16x32_bf16(kf1, qf1, s0, 0, 0, 0);
        s1 = __builtin_amdgcn_mfma_f32_16x16x32_bf16(kf2, qf0, s1, 0, 0, 0);
        s1 = __builtin_amdgcn_mfma_f32_16x16x32_bf16(kf3, qf1, s1, 0, 0, 0);
        __builtin_amdgcn_s_setprio(0);
        // s0[r] = score_log2(q=cl, k = 4g+r); s1[r] = same at k = 16+4g+r

        // ---- online softmax (log2 domain) for q-row cl ----
        float tmax = fmaxf(fmaxf(fmaxf(s0[0], s0[1]), fmaxf(s0[2], s0[3])),
                           fmaxf(fmaxf(s1[0], s1[1]), fmaxf(s1[2], s1[3])));
        tmax = fmaxf(tmax, __shfl_xor(tmax, 16));
        tmax = fmaxf(tmax, __shfl_xor(tmax, 32));

        // defer-max: exact skip (THR=0) when no row's max grew
        if (!__all(tmax <= mrun)) {
            const float mnew = fmaxf(mrun, tmax);
            const float corr = fast_exp2(mrun - mnew);   // first iter: 0
            lsum *= corr;
#pragma unroll
            for (int r = 0; r < 4; ++r) {
                const float cr = __shfl(corr, 4*g + r);
#pragma unroll
                for (int nt = 0; nt < 4; ++nt) acc[nt][r] *= cr;
            }
            mrun = mnew;
        }

#pragma unroll
        for (int r = 0; r < 4; ++r) {
            const float p0 = fast_exp2(s0[r] - mrun);
            const float p1 = fast_exp2(s1[r] - mrun);
            s0[r] = p0; s1[r] = p1;
            lsum += p0 + p1;
        }

        // ---- pack P: pa[e] = P[cl][16*(e>>2) + 4g + (e&3)] ----
        bf16x8 pa;
#pragma unroll
        for (int e = 0; e < 4; ++e) { pa[e] = (__bf16)s0[e]; pa[e+4] = (__bf16)s1[e]; }

        // ---- PV: one 16B V-frag + one MFMA per nt (k-permuted VT) ----
        bf16x8 vf0 = *reinterpret_cast<const bf16x8*>(Vl + ( 0 + cl)*64 + vswz);
        bf16x8 vf1 = *reinterpret_cast<const bf16x8*>(Vl + (16 + cl)*64 + vswz);
        bf16x8 vf2 = *reinterpret_cast<const bf16x8*>(Vl + (32 + cl)*64 + vswz);
        bf16x8 vf3 = *reinterpret_cast<const bf16x8*>(Vl + (48 + cl)*64 + vswz);
        __builtin_amdgcn_s_setprio(1);
        acc[0] = __builtin_amdgcn_mfma_f32_16x16x32_bf16(pa, vf0, acc[0], 0, 0, 0);
        acc[1] = __builtin_amdgcn_mfma_f32_16x16x32_bf16(pa, vf1, acc[1], 0, 0, 0);
        acc[2] = __builtin_amdgcn_mfma_f32_16x16x32_bf16(pa, vf2, acc[2], 0, 0, 0);
        acc[3] = __builtin_amdgcn_mfma_f32_16x16x32_bf16(pa, vf3, acc[3], 0, 0, 0);
        __builtin_amdgcn_s_setprio(0);

        // counted wait: only stage(n+1) must be complete (issued last iter);
        // the just-issued stage(n+2) pair stays in flight across the barrier.
        if (n < 30) {
            asm volatile("s_waitcnt vmcnt(2)" ::: "memory");
        } else {
            asm volatile("s_waitcnt vmcnt(0)" ::: "memory");
        }
        __builtin_amdgcn_s_barrier();
        if (++bcur == 3) bcur = 0;
    }

    // deferred psum cross-lane reduce (row cl spread over lanes cl+16g)
    lsum += __shfl_xor(lsum, 16);
    lsum += __shfl_xor(lsum, 32);

    // ---- 4-way wk merge through LDS (aliases dead staging buffers) ----
    float* lacc = (float*)smem;                  // [12][16][65] f32
    float* lm   = (float*)(smem + 49920);
    float* ll   = (float*)(smem + 50688);

    if (wk > 0) {
        const int pi = (wk - 1) * 4 + wq;
        if (lane < 16) { lm[pi*16 + lane] = mrun; ll[pi*16 + lane] = lsum; }
#pragma unroll
        for (int nt = 0; nt < 4; ++nt)
#pragma unroll
            for (int r = 0; r < 4; ++r)
                lacc[pi*1040 + (4*g + r)*65 + nt*16 + cl] = acc[nt][r];
    }
    __syncthreads();

    if (wk == 0) {
#pragma unroll
        for (int r = 0; r < 4; ++r) {
            const int ro = 4*g + r;
            const float mo = __shfl(mrun, ro);
            const float lo = __shfl(lsum, ro);
            const float m1 = lm[(wq     )*16 + ro], l1 = ll[(wq     )*16 + ro];
            const float m2 = lm[(4 + wq )*16 + ro], l2 = ll[(4 + wq )*16 + ro];
            const float m3 = lm[(8 + wq )*16 + ro], l3 = ll[(8 + wq )*16 + ro];
            const float M  = fmaxf(fmaxf(mo, m1), fmaxf(m2, m3));
            const float f0 = fast_exp2(mo - M);
            const float f1 = fast_exp2(m1 - M);
            const float f2 = fast_exp2(m2 - M);
            const float f3 = fast_exp2(m3 - M);
            const float inv = 1.f / (lo*f0 + l1*f1 + l2*f2 + l3*f3);
#pragma unroll
            for (int nt = 0; nt < 4; ++nt) {
                const int col = nt*16 + cl;
                const float val = acc[nt][r]*f0
                    + lacc[(wq    )*1040 + ro*65 + col]*f1
                    + lacc[(4 + wq)*1040 + ro*65 + col]*f2
                    + lacc[(8 + wq)*1040 + ro*65 + col]*f3;
                out[((long)b * SEQ + qbase + wq*16 + ro) * DIM + col] = val * inv;
            }
        }
    }
}

// ---------------------------------------------------------------------------
extern "C" void kernel_launch(void* const* d_in, const int* in_sizes, int n_in,
                              void* d_out, int out_size, void* d_ws, size_t ws_size,
                              hipStream_t stream)
{
    const float* x = (const float*)d_in[0];
    const float* w = (const float*)d_in[1];
    float* out = (float*)d_out;

    char* ws = (char*)d_ws;
    const size_t sz = (size_t)NB * SEQ * DIM * sizeof(__bf16);  // 2 MiB each
    __bf16* Qb   = (__bf16*)(ws);
    __bf16* Kb   = (__bf16*)(ws + sz);
    __bf16* VTb  = (__bf16*)(ws + 2 * sz);
    __bf16* WT   = (__bf16*)(ws + 3 * sz);              // 24 KiB
    float*  ivt  = (float*)(ws + 3 * sz + 24 * 1024);   // 256 B

    wprep_kernel<<<3 * DIM * DIM / 256, 256, 0, stream>>>(w, WT, ivt);

    qkv_prep_kernel<<<NB * SEQ / 64, 256, 0, stream>>>(x, WT, ivt, Qb, Kb, VTb);

    attn_kernel<<<NB * SEQ / 64, 1024, 0, stream>>>(Qb, Kb, VTb, out);
}